// Round 1
// baseline (96.041 us; speedup 1.0000x reference)
//
#include <hip/hip_runtime.h>

#define NV_N 400
#define NN 160000
#define EPSV 1e-4f

// ws offsets in floats
#define OFF_A    0         // 160000  A matrix (flat e = i*400+j)
#define OFF_P2   160000    // 12800
#define OFF_Q2   172800    // 12800
#define OFF_R    185600    // 25600
#define OFF_S    211200    // 25600
#define OFF_V4   236800    // 25600
#define OFF_AR   262400    // 25600  alpha_raw
#define OFF_NV   288000    // 400    norm_value
#define OFF_DV   288400    // 400    d vector
#define OFF_GMAX 288800    // 1 (uint bits of max|alpha_raw|)
#define OFF_PART 288832    // KB * 400*64 partials

// K1: per-node precompute. grid 400, block 64.
__global__ __launch_bounds__(64) void k1_node_pre(
    const float* __restrict__ NEE, const float* __restrict__ NFN,
    const float* __restrict__ W_n2e, const float* __restrict__ b_n2e,
    const float* __restrict__ W_n2e2, const float* __restrict__ b_n2e2,
    const float* __restrict__ W_ev1, const float* __restrict__ b_ev1,
    const float* __restrict__ W4,
    const float* __restrict__ W_ft1, const float* __restrict__ b_ft1,
    const float* __restrict__ W_ft2, const float* __restrict__ b_ft2,
    float* __restrict__ ws)
{
    __shared__ float xne[64], xnf[64], tP[64], tQ[64], hidN[32], hidF[32];
    int i = blockIdx.x, dd = threadIdx.x;
    float x_ne = NEE[i*64+dd];
    float x_nf = NFN[i*64+dd];
    xne[dd] = x_ne; xnf[dd] = x_nf;
    if (i == 0 && dd == 0) ((unsigned*)(ws + OFF_GMAX))[0] = 0u;  // zero before k4 runs
    __syncthreads();
    float pv = b_n2e[dd], qv = 0.f, rv = b_n2e2[dd], sv = 0.f, v4 = 0.f;
    for (int k = 0; k < 64; ++k) {
        float xk = xne[k];
        pv += xk * W_n2e[k*64+dd];
        qv += xk * W_n2e[(64+k)*64+dd];
        rv += xk * W_n2e2[k*64+dd];
        sv += xk * W_n2e2[(64+k)*64+dd];
        v4 += fmaxf(xnf[k]-xk, 0.f) * W4[k*64+dd];
    }
    tP[dd] = pv; tQ[dd] = qv;
    ws[OFF_R  + i*64+dd] = rv;
    ws[OFF_S  + i*64+dd] = sv;
    ws[OFF_V4 + i*64+dd] = v4;
    if (dd < 32) {
        float hn = b_ft1[dd], hf = b_ft1[dd];
        for (int k = 0; k < 64; ++k) { hn += xne[k]*W_ft1[k*32+dd]; hf += xnf[k]*W_ft1[k*32+dd]; }
        hidN[dd] = fmaxf(hn, 0.f); hidF[dd] = fmaxf(hf, 0.f);
    }
    __syncthreads();
    if (dd < 32) {
        float p2 = b_ev1[dd], q2 = 0.f;
        for (int c = 0; c < 64; ++c) { p2 += tP[c]*W_ev1[c*32+dd]; q2 += tQ[c]*W_ev1[c*32+dd]; }
        ws[OFF_P2 + i*32+dd] = p2;
        ws[OFF_Q2 + i*32+dd] = q2;
    }
    if (dd == 0) {
        float num = b_ft2[0], den = b_ft2[0];
        for (int c = 0; c < 32; ++c) { num += hidN[c]*W_ft2[c]; den += hidF[c]*W_ft2[c]; }
        float dv = (den == 0.f) ? EPSV : den;
        ws[OFF_NV + i] = num / dv;
    }
}

// K3: A matrix + row degree. grid 400 (row i), block 256.
__global__ __launch_bounds__(256) void k3_Amat(
    const float* __restrict__ W_ev2, const float* __restrict__ b_ev2,
    float* __restrict__ ws)
{
    __shared__ float p2s[32], wev2[32], red[256];
    int i = blockIdx.x, t = threadIdx.x;
    if (t < 32) { p2s[t] = ws[OFF_P2 + i*32+t]; wev2[t] = W_ev2[t]; }
    __syncthreads();
    float b2 = b_ev2[0];
    float s = 0.f;
    for (int j = t; j < NV_N; j += 256) {
        float v = b2;
        #pragma unroll
        for (int c = 0; c < 32; ++c) {
            float h = p2s[c] + ws[OFF_Q2 + j*32+c];
            v += fmaxf(h, 0.f) * wev2[c];
        }
        float a = fmaxf(v, 0.f);
        ws[OFF_A + i*NV_N + j] = a;
        s += a;
    }
    red[t] = s; __syncthreads();
    for (int st = 128; st > 0; st >>= 1) { if (t < st) red[t] += red[t+st]; __syncthreads(); }
    if (t == 0) ws[OFF_DV + i] = rsqrtf(fmaxf(red[0], EPSV));
}

// K4: massage_conv -> alpha_raw + global absmax. grid 400, block 64.
__global__ __launch_bounds__(64) void k4_alpha(
    const float* __restrict__ NEE,
    const float* __restrict__ W3,
    const float* __restrict__ W_alpha, const float* __restrict__ b_alpha,
    float* __restrict__ ws)
{
    __shared__ float nm[64], mc[64];
    int i = blockIdx.x, dd = threadIdx.x;
    float di = ws[OFF_DV + i];
    float acc = 0.f;
    for (int j = 0; j < NV_N; ++j) {
        float coef = ws[OFF_A + i*NV_N + j] * ws[OFF_DV + j];
        acc += coef * NEE[j*64 + dd];
    }
    nm[dd] = acc * di;
    __syncthreads();
    float acc2 = 0.f;
    for (int c = 0; c < 64; ++c) acc2 += nm[c] * W3[c*64+dd];
    mc[dd] = acc2;
    __syncthreads();
    float ar = b_alpha[dd];
    for (int c = 0; c < 64; ++c) ar += mc[c] * W_alpha[c*64+dd];
    ws[OFF_AR + i*64+dd] = ar;
    atomicMax((unsigned*)(ws + OFF_GMAX), __float_as_uint(fabsf(ar)));
}

// K6: pred_edge + indicator output. grid NN/4, block 256 (1 wave = 1 edge).
__global__ __launch_bounds__(256) void k6_edge(
    const float* __restrict__ NEE,
    const float* __restrict__ W_e2e, const float* __restrict__ b_e2e,
    const float* __restrict__ ws,
    float* __restrict__ out)
{
    int t = threadIdx.x, lane = t & 63, w = t >> 6;
    int e = blockIdx.x * 4 + w;
    float a = ws[OFF_A + e];                  // wave-uniform
    bool ind = (a >= 1.0f);
    float* outrow = out + (size_t)(NV_N + e) * 64;
    if (lane == 0) out[(size_t)160400*64 + e] = ind ? 1.f : 0.f;
    if (!ind) { outrow[lane] = 0.f; return; }  // wave-uniform branch
    int ii = e / NV_N, jj = e - ii * NV_N;
    float emb = NEE[(size_t)(NV_N + e)*64 + lane];
    float v = b_e2e[lane];
    #pragma unroll
    for (int c = 0; c < 64; ++c) v += __shfl(emb, c) * W_e2e[c*64 + lane];
    v += ws[OFF_R + ii*64 + lane] + ws[OFF_S + jj*64 + lane];
    outrow[lane] = v;
}

// K7: sparse Aggr_edge partials. grid (KB, 7), block 256.
// wave = (lane=d, rq -> 16 rows). Each wave scans its kb e-partition via ballot,
// recomputes gamma in-register (softmax over 64 lanes), gathers A_ne column.
__global__ __launch_bounds__(256) void k7_aggr(
    const float* __restrict__ NEE,
    const float* __restrict__ A_ne,
    const float* __restrict__ W_gamma, const float* __restrict__ b_gamma,
    float* __restrict__ ws)
{
    int t = threadIdx.x, lane = t & 63, rq = t >> 6;
    int kb = blockIdx.x, rb = blockIdx.y;
    int KB = gridDim.x;
    int CH = (NN + KB - 1) / KB;
    int e0 = kb * CH;
    int e1 = e0 + CH; if (e1 > NN) e1 = NN;
    float acc[16];
    #pragma unroll
    for (int r = 0; r < 16; ++r) acc[r] = 0.f;
    float bg = b_gamma[lane];
    for (int base = e0; base < e1; base += 64) {
        int ee = base + lane;
        float fl = (ee < e1) ? ws[OFF_A + ee] : 0.f;
        unsigned long long m = __ballot(fl >= 1.0f);
        while (m) {
            int b = __builtin_ctzll(m); m &= m - 1;
            int e = base + b;
            float emb = NEE[(size_t)(NV_N + e)*64 + lane];
            float g = bg;
            #pragma unroll
            for (int c = 0; c < 64; ++c) g += __shfl(emb, c) * W_gamma[c*64 + lane];
            float mx = g;
            #pragma unroll
            for (int off = 32; off > 0; off >>= 1) mx = fmaxf(mx, __shfl_xor(mx, off));
            float p = __expf(g - mx);
            float ssum = p;
            #pragma unroll
            for (int off = 32; off > 0; off >>= 1) ssum += __shfl_xor(ssum, off);
            float wv = (p / ssum) * emb;
            #pragma unroll
            for (int r = 0; r < 16; ++r) {
                int n = rb*64 + rq*16 + r;
                float a = (n < NV_N) ? A_ne[(size_t)n*NN + e] : 0.f;
                acc[r] = fmaf(a, wv, acc[r]);
            }
        }
    }
    #pragma unroll
    for (int r = 0; r < 16; ++r) {
        int n = rb*64 + rq*16 + r;
        if (n < NV_N) ws[OFF_PART + ((size_t)kb*NV_N + n)*64 + lane] = acc[r];
    }
}

// K8: final pred_node. grid 400, block 64.
__global__ __launch_bounds__(64) void k8_node(
    const float* __restrict__ ws_c, int KB,
    float* __restrict__ out)
{
    int i = blockIdx.x, dd = threadIdx.x;
    float amax = fmaxf(__uint_as_float(((const unsigned*)(ws_c + OFF_GMAX))[0]), EPSV);
    float v = (ws_c[OFF_AR + i*64+dd] / amax) * ws_c[OFF_NV + i] * ws_c[OFF_V4 + i*64+dd];
    float ssum = 0.f;
    for (int kb = 0; kb < KB; ++kb) ssum += ws_c[OFF_PART + ((size_t)kb*NV_N + i)*64 + dd];
    out[i*64 + dd] = v + ssum;
}

extern "C" void kernel_launch(void* const* d_in, const int* in_sizes, int n_in,
                              void* d_out, int out_size, void* d_ws, size_t ws_size,
                              hipStream_t stream) {
    const float* NEE     = (const float*)d_in[1];
    const float* NFN     = (const float*)d_in[2];
    const float* A_ne    = (const float*)d_in[3];
    const float* W_alpha = (const float*)d_in[5];
    const float* b_alpha = (const float*)d_in[6];
    const float* W_gamma = (const float*)d_in[7];
    const float* b_gamma = (const float*)d_in[8];
    const float* W_n2e   = (const float*)d_in[9];
    const float* b_n2e   = (const float*)d_in[10];
    const float* W_ev1   = (const float*)d_in[11];
    const float* b_ev1   = (const float*)d_in[12];
    const float* W_ev2   = (const float*)d_in[13];
    const float* b_ev2   = (const float*)d_in[14];
    const float* W_ft1   = (const float*)d_in[15];
    const float* b_ft1   = (const float*)d_in[16];
    const float* W_ft2   = (const float*)d_in[17];
    const float* b_ft2   = (const float*)d_in[18];
    const float* W3      = (const float*)d_in[19];
    const float* W4      = (const float*)d_in[20];
    const float* W_e2e   = (const float*)d_in[21];
    const float* b_e2e   = (const float*)d_in[22];
    const float* W_n2e2  = (const float*)d_in[23];
    const float* b_n2e2  = (const float*)d_in[24];
    float* out = (float*)d_out;
    float* ws  = (float*)d_ws;

    // split-K width for the Aggr partials, adapted to ws_size
    long long avail = (long long)(ws_size / 4) - OFF_PART;
    int KB = 1;
    if (avail > 0) {
        KB = (int)(avail / (NV_N * 64));
        if (KB > 32) KB = 32;
        if (KB < 1) KB = 1;
    }

    hipLaunchKernelGGL(k1_node_pre, dim3(NV_N), dim3(64), 0, stream,
        NEE, NFN, W_n2e, b_n2e, W_n2e2, b_n2e2, W_ev1, b_ev1, W4,
        W_ft1, b_ft1, W_ft2, b_ft2, ws);
    hipLaunchKernelGGL(k3_Amat, dim3(NV_N), dim3(256), 0, stream,
        W_ev2, b_ev2, ws);
    hipLaunchKernelGGL(k4_alpha, dim3(NV_N), dim3(64), 0, stream,
        NEE, W3, W_alpha, b_alpha, ws);
    hipLaunchKernelGGL(k6_edge, dim3(NN/4), dim3(256), 0, stream,
        NEE, W_e2e, b_e2e, ws, out);
    hipLaunchKernelGGL(k7_aggr, dim3(KB, 7), dim3(256), 0, stream,
        NEE, A_ne, W_gamma, b_gamma, ws);
    hipLaunchKernelGGL(k8_node, dim3(NV_N), dim3(64), 0, stream,
        ws, KB, out);
}

// Round 2
// 44.150 us; speedup vs baseline: 2.1754x; 2.1754x over previous
//
#include <hip/hip_runtime.h>

#define NV_N 400
#define NN   160000
#define EPSV 1e-4f
#define IND_BASE ((size_t)160400 * 64)

// ws offsets in floats
#define OFF_A    0         // 160000  A matrix (flat e = i*400+j)
#define OFF_P2   160000    // 12800
#define OFF_Q2   172800    // 12800
#define OFF_R    185600    // 25600
#define OFF_S    211200    // 25600
#define OFF_V4   236800    // 25600
#define OFF_AR   262400    // 25600  alpha_raw
#define OFF_NV   288000    // 400    norm_value
#define OFF_DV   288400    // 400    1/sqrt(deg)
#define OFF_GMAX 288800    // 1 (uint bits of max|alpha_raw|)
#define OFF_CNT  288832    // 400 (int) per-row active count
#define OFF_LIST 289280    // up to 160000 (int) compact active-edge list
#define OFF_WV   449280    // cap*64 gamma-weighted embeddings

// K1: per-node precompute. grid 400, block 64.
__global__ __launch_bounds__(64) void k1_node_pre(
    const float* __restrict__ NEE, const float* __restrict__ NFN,
    const float* __restrict__ W_n2e, const float* __restrict__ b_n2e,
    const float* __restrict__ W_n2e2, const float* __restrict__ b_n2e2,
    const float* __restrict__ W_ev1, const float* __restrict__ b_ev1,
    const float* __restrict__ W4,
    const float* __restrict__ W_ft1, const float* __restrict__ b_ft1,
    const float* __restrict__ W_ft2, const float* __restrict__ b_ft2,
    float* __restrict__ ws)
{
    __shared__ float xne[64], xnf[64], tP[64], tQ[64], hidN[32], hidF[32];
    int i = blockIdx.x, dd = threadIdx.x;
    float x_ne = NEE[i*64+dd];
    float x_nf = NFN[i*64+dd];
    xne[dd] = x_ne; xnf[dd] = x_nf;
    if (i == 0 && dd == 0) ((unsigned*)(ws + OFF_GMAX))[0] = 0u;  // zero before K3
    __syncthreads();
    float pv = b_n2e[dd], qv = 0.f, rv = b_n2e2[dd], sv = 0.f, v4 = 0.f;
    for (int k = 0; k < 64; ++k) {
        float xk = xne[k];
        pv += xk * W_n2e[k*64+dd];
        qv += xk * W_n2e[(64+k)*64+dd];
        rv += xk * W_n2e2[k*64+dd];
        sv += xk * W_n2e2[(64+k)*64+dd];
        v4 += fmaxf(xnf[k]-xk, 0.f) * W4[k*64+dd];
    }
    tP[dd] = pv; tQ[dd] = qv;
    ws[OFF_R  + i*64+dd] = rv;
    ws[OFF_S  + i*64+dd] = sv;
    ws[OFF_V4 + i*64+dd] = v4;
    if (dd < 32) {
        float hn = b_ft1[dd], hf = b_ft1[dd];
        for (int k = 0; k < 64; ++k) { hn += xne[k]*W_ft1[k*32+dd]; hf += xnf[k]*W_ft1[k*32+dd]; }
        hidN[dd] = fmaxf(hn, 0.f); hidF[dd] = fmaxf(hf, 0.f);
    }
    __syncthreads();
    if (dd < 32) {
        float p2 = b_ev1[dd], q2 = 0.f;
        for (int c = 0; c < 64; ++c) { p2 += tP[c]*W_ev1[c*32+dd]; q2 += tQ[c]*W_ev1[c*32+dd]; }
        ws[OFF_P2 + i*32+dd] = p2;
        ws[OFF_Q2 + i*32+dd] = q2;
    }
    if (dd == 0) {
        float num = b_ft2[0], den = b_ft2[0];
        for (int c = 0; c < 32; ++c) { num += hidN[c]*W_ft2[c]; den += hidF[c]*W_ft2[c]; }
        float dv = (den == 0.f) ? EPSV : den;
        ws[OFF_NV + i] = num / dv;
    }
}

// K2: A row + degree + count + indicator + pred_edge (zero-fill + active rows).
// grid 400 (row i), block 256.
__global__ __launch_bounds__(256) void k2_row(
    const float* __restrict__ NEE,
    const float* __restrict__ W_ev2, const float* __restrict__ b_ev2,
    const float* __restrict__ W_e2e, const float* __restrict__ b_e2e,
    float* __restrict__ ws, float* __restrict__ out)
{
    __shared__ float p2s[32], wev2[32], red[256];
    __shared__ int rcnt[256];
    __shared__ unsigned char flag[NV_N];
    __shared__ int act[NV_N];
    __shared__ int s_cnt;
    int i = blockIdx.x, t = threadIdx.x;
    if (t < 32) { p2s[t] = ws[OFF_P2 + i*32+t]; wev2[t] = W_ev2[t]; }
    __syncthreads();
    float b2 = b_ev2[0];
    float s = 0.f; int cc = 0;
    for (int j = t; j < NV_N; j += 256) {
        float v = b2;
        #pragma unroll
        for (int c = 0; c < 32; ++c) {
            float h = p2s[c] + ws[OFF_Q2 + j*32+c];
            v += fmaxf(h, 0.f) * wev2[c];
        }
        float a = fmaxf(v, 0.f);
        ws[OFF_A + i*NV_N + j] = a;
        bool f = (a >= 1.0f);
        flag[j] = f ? 1 : 0;
        out[IND_BASE + (size_t)i*NV_N + j] = f ? 1.f : 0.f;
        s += a; cc += f ? 1 : 0;
    }
    red[t] = s; rcnt[t] = cc;
    __syncthreads();
    for (int st = 128; st > 0; st >>= 1) {
        if (t < st) { red[t] += red[t+st]; rcnt[t] += rcnt[t+st]; }
        __syncthreads();
    }
    if (t == 0) {
        ws[OFF_DV + i] = rsqrtf(fmaxf(red[0], EPSV));
        ((int*)ws)[OFF_CNT + i] = rcnt[0];
    }
    // wave 0: build this row's ordered active list in smem
    if (t < 64) {
        int base = 0;
        for (int ch = 0; ch < 7; ++ch) {
            int j = ch*64 + t;
            bool f = (j < NV_N) && (flag[j] != 0);
            unsigned long long m = __ballot(f);
            if (f) {
                int pre = __popcll(m & ((1ull << t) - 1ull));
                act[base + pre] = j;
            }
            base += __popcll(m);
        }
        if (t == 0) s_cnt = base;
    }
    // zero-fill this row-block's 400 pred_edge rows (contiguous 100 KB)
    float4 z4 = make_float4(0.f, 0.f, 0.f, 0.f);
    float4* orow = (float4*)(out + (NV_N + (size_t)i*NV_N) * 64);
    for (int q = t; q < NV_N*64/4; q += 256) orow[q] = z4;
    __syncthreads();
    // active rows: one wave per active edge (round-robin)
    int cnt = s_cnt, lane = t & 63, w = t >> 6;
    for (int k = w; k < cnt; k += 4) {
        int j = act[k];
        int e = i*NV_N + j;
        float emb = NEE[(size_t)(NV_N + e)*64 + lane];
        float v = b_e2e[lane] + ws[OFF_R + i*64 + lane] + ws[OFF_S + j*64 + lane];
        #pragma unroll
        for (int c = 0; c < 64; ++c) v += __shfl(emb, c) * W_e2e[c*64 + lane];
        out[(size_t)(NV_N + e)*64 + lane] = v;
    }
}

// K3: alpha chain + global compaction + wv (gamma-weighted emb) per active edge.
// grid 400 (node/row i), block 256.
__global__ __launch_bounds__(256) void k3_alpha_compact(
    const float* __restrict__ NEE,
    const float* __restrict__ W3,
    const float* __restrict__ W_alpha, const float* __restrict__ b_alpha,
    const float* __restrict__ W_gamma, const float* __restrict__ b_gamma,
    float* __restrict__ ws, int cap)
{
    __shared__ float part[4][64];
    __shared__ int red[256];
    __shared__ int s_off;
    int i = blockIdx.x, t = threadIdx.x, lane = t & 63, w = t >> 6;
    // offset = sum of counts[r] for r < i
    int os = 0;
    for (int r = t; r < i; r += 256) os += ((const int*)ws)[OFF_CNT + r];
    red[t] = os; __syncthreads();
    for (int st = 128; st > 0; st >>= 1) { if (t < st) red[t] += red[t+st]; __syncthreads(); }
    if (t == 0) s_off = red[0];
    // alpha partials: wave w covers j in [w*100, w*100+100)
    float acc = 0.f;
    for (int j = w*100; j < w*100 + 100; ++j) {
        float coef = ws[OFF_A + i*NV_N + j] * ws[OFF_DV + j];
        acc += coef * NEE[j*64 + lane];
    }
    part[w][lane] = acc;
    __syncthreads();   // also makes s_off visible
    if (w == 0) {
        // nm -> mc -> ar entirely in wave 0 registers + shfl
        float nm = (part[0][lane] + part[1][lane] + part[2][lane] + part[3][lane]) * ws[OFF_DV + i];
        float mc = 0.f;
        #pragma unroll
        for (int c = 0; c < 64; ++c) mc += __shfl(nm, c) * W3[c*64 + lane];
        float ar = b_alpha[lane];
        #pragma unroll
        for (int c = 0; c < 64; ++c) ar += __shfl(mc, c) * W_alpha[c*64 + lane];
        ws[OFF_AR + i*64 + lane] = ar;
        float mx = fabsf(ar);
        #pragma unroll
        for (int off = 32; off > 0; off >>= 1) mx = fmaxf(mx, __shfl_xor(mx, off));
        if (lane == 0) atomicMax((unsigned*)(ws + OFF_GMAX), __float_as_uint(mx));
    } else if (w == 1) {
        // ordered compaction of this row into the global list
        int base = 0;
        for (int ch = 0; ch < 7; ++ch) {
            int j = ch*64 + lane;
            float a = (j < NV_N) ? ws[OFF_A + i*NV_N + j] : 0.f;
            bool f = (a >= 1.0f);
            unsigned long long m = __ballot(f);
            if (f) {
                int pre = __popcll(m & ((1ull << lane) - 1ull));
                int slot = s_off + base + pre;
                if (slot < cap) ((int*)ws)[OFF_LIST + slot] = i*NV_N + j;
            }
            base += __popcll(m);
        }
    }
    __syncthreads();
    // wv for this row's actives: wave w takes k = w, w+4, ...
    int cnt = ((const int*)ws)[OFF_CNT + i];
    for (int k = w; k < cnt; k += 4) {
        int slot = s_off + k;
        if (slot >= cap) break;
        int e = ((const int*)ws)[OFF_LIST + slot];
        float emb = NEE[(size_t)(NV_N + e)*64 + lane];
        float g = b_gamma[lane];
        #pragma unroll
        for (int c = 0; c < 64; ++c) g += __shfl(emb, c) * W_gamma[c*64 + lane];
        float mx = g;
        #pragma unroll
        for (int off = 32; off > 0; off >>= 1) mx = fmaxf(mx, __shfl_xor(mx, off));
        float p = __expf(g - mx);
        float ssum = p;
        #pragma unroll
        for (int off = 32; off > 0; off >>= 1) ssum += __shfl_xor(ssum, off);
        ws[OFF_WV + (size_t)slot*64 + lane] = (p / ssum) * emb;
    }
}

// K4: gather-GEMM over compact list + final pred_node. grid 400, block 256.
__global__ __launch_bounds__(256) void k4_final(
    const float* __restrict__ A_ne,
    const float* __restrict__ ws, int cap,
    float* __restrict__ out)
{
    __shared__ float part[4][64];
    __shared__ int red[256];
    int i = blockIdx.x, t = threadIdx.x, lane = t & 63, w = t >> 6;
    int os = 0;
    for (int r = t; r < NV_N; r += 256) os += ((const int*)ws)[OFF_CNT + r];
    red[t] = os; __syncthreads();
    for (int st = 128; st > 0; st >>= 1) { if (t < st) red[t] += red[t+st]; __syncthreads(); }
    int nnz = red[0]; if (nnz > cap) nnz = cap;
    float acc = 0.f;
    for (int l = w; l < nnz; l += 4) {
        int e = ((const int*)ws)[OFF_LIST + l];
        float a = A_ne[(size_t)i*NN + e];          // wave-uniform broadcast load
        acc += a * ws[OFF_WV + (size_t)l*64 + lane];
    }
    part[w][lane] = acc;
    __syncthreads();
    if (w == 0) {
        float aggr = part[0][lane] + part[1][lane] + part[2][lane] + part[3][lane];
        float amax = fmaxf(__uint_as_float(((const unsigned*)(ws + OFF_GMAX))[0]), EPSV);
        float v = (ws[OFF_AR + i*64 + lane] / amax) * ws[OFF_NV + i] * ws[OFF_V4 + i*64 + lane];
        out[i*64 + lane] = v + aggr;
    }
}

extern "C" void kernel_launch(void* const* d_in, const int* in_sizes, int n_in,
                              void* d_out, int out_size, void* d_ws, size_t ws_size,
                              hipStream_t stream) {
    const float* NEE     = (const float*)d_in[1];
    const float* NFN     = (const float*)d_in[2];
    const float* A_ne    = (const float*)d_in[3];
    const float* W_alpha = (const float*)d_in[5];
    const float* b_alpha = (const float*)d_in[6];
    const float* W_gamma = (const float*)d_in[7];
    const float* b_gamma = (const float*)d_in[8];
    const float* W_n2e   = (const float*)d_in[9];
    const float* b_n2e   = (const float*)d_in[10];
    const float* W_ev1   = (const float*)d_in[11];
    const float* b_ev1   = (const float*)d_in[12];
    const float* W_ev2   = (const float*)d_in[13];
    const float* b_ev2   = (const float*)d_in[14];
    const float* W_ft1   = (const float*)d_in[15];
    const float* b_ft1   = (const float*)d_in[16];
    const float* W_ft2   = (const float*)d_in[17];
    const float* b_ft2   = (const float*)d_in[18];
    const float* W3      = (const float*)d_in[19];
    const float* W4      = (const float*)d_in[20];
    const float* W_e2e   = (const float*)d_in[21];
    const float* b_e2e   = (const float*)d_in[22];
    const float* W_n2e2  = (const float*)d_in[23];
    const float* b_n2e2  = (const float*)d_in[24];
    float* out = (float*)d_out;
    float* ws  = (float*)d_ws;

    // capacity of the compact edge list given ws_size (evidence: ws = 1 GB)
    long long cap_ll = ((long long)(ws_size / 4) - OFF_WV) / 64;
    int cap = (cap_ll > NN) ? NN : (cap_ll < 0 ? 0 : (int)cap_ll);

    hipLaunchKernelGGL(k1_node_pre, dim3(NV_N), dim3(64), 0, stream,
        NEE, NFN, W_n2e, b_n2e, W_n2e2, b_n2e2, W_ev1, b_ev1, W4,
        W_ft1, b_ft1, W_ft2, b_ft2, ws);
    hipLaunchKernelGGL(k2_row, dim3(NV_N), dim3(256), 0, stream,
        NEE, W_ev2, b_ev2, W_e2e, b_e2e, ws, out);
    hipLaunchKernelGGL(k3_alpha_compact, dim3(NV_N), dim3(256), 0, stream,
        NEE, W3, W_alpha, b_alpha, W_gamma, b_gamma, ws, cap);
    hipLaunchKernelGGL(k4_final, dim3(NV_N), dim3(256), 0, stream,
        A_ne, ws, cap, out);
}

// Round 3
// 41.909 us; speedup vs baseline: 2.2917x; 1.0535x over previous
//
#include <hip/hip_runtime.h>

#define NV_N 400
#define NN   160000
#define EPSV 1e-4f
#define IND_BASE ((size_t)160400 * 64)

// ws offsets in floats
#define OFF_A    0         // 160000  A matrix (flat e = i*400+j)
#define OFF_P2   160000    // 12800
#define OFF_Q2   172800    // 12800
#define OFF_R    185600    // 25600
#define OFF_S    211200    // 25600
#define OFF_V4   236800    // 25600
#define OFF_AR   262400    // 25600  alpha_raw
#define OFF_NV   288000    // 400    norm_value
#define OFF_DV   288400    // 400    1/sqrt(deg)
#define OFF_GMAX 288800    // 1 (uint bits of max|alpha_raw|)
#define OFF_CNT  288832    // 400 (int) per-row active count
#define OFF_LIST 289280    // up to 160000 (int) compact active-edge list
#define OFF_WV   449280    // cap*64 gamma-weighted embeddings

// K0: wide zero-fill of pred_edge (40 MB) fused with per-node precompute.
// grid 2048, block 256. Blocks < 400 also do node i = blockIdx work.
__global__ __launch_bounds__(256) void k0_fill_pre(
    const float* __restrict__ NEE, const float* __restrict__ NFN,
    const float* __restrict__ W_n2e, const float* __restrict__ b_n2e,
    const float* __restrict__ W_n2e2, const float* __restrict__ b_n2e2,
    const float* __restrict__ W_ev1, const float* __restrict__ b_ev1,
    const float* __restrict__ W4,
    const float* __restrict__ W_ft1, const float* __restrict__ b_ft1,
    const float* __restrict__ W_ft2, const float* __restrict__ b_ft2,
    float* __restrict__ ws, float* __restrict__ out)
{
    __shared__ float xne[64], xnf[64], tP[64], tQ[64], hidN[32], hidF[32];
    int b = blockIdx.x, t = threadIdx.x;
    if (b < NV_N) {
        int i = b;
        if (t < 64) { xne[t] = NEE[i*64+t]; xnf[t] = NFN[i*64+t]; }
        if (b == 0 && t == 0) ((unsigned*)(ws + OFF_GMAX))[0] = 0u;
        __syncthreads();
        if (t < 64) {
            int dd = t;
            float pv = b_n2e[dd], qv = 0.f, rv = b_n2e2[dd], sv = 0.f, v4 = 0.f;
            for (int k = 0; k < 64; ++k) {
                float xk = xne[k];
                pv += xk * W_n2e[k*64+dd];
                qv += xk * W_n2e[(64+k)*64+dd];
                rv += xk * W_n2e2[k*64+dd];
                sv += xk * W_n2e2[(64+k)*64+dd];
                v4 += fmaxf(xnf[k]-xk, 0.f) * W4[k*64+dd];
            }
            tP[dd] = pv; tQ[dd] = qv;
            ws[OFF_R  + i*64+dd] = rv;
            ws[OFF_S  + i*64+dd] = sv;
            ws[OFF_V4 + i*64+dd] = v4;
        } else if (t >= 64 && t < 96) {
            int dd = t - 64;
            float hn = b_ft1[dd], hf = b_ft1[dd];
            for (int k = 0; k < 64; ++k) { hn += xne[k]*W_ft1[k*32+dd]; hf += xnf[k]*W_ft1[k*32+dd]; }
            hidN[dd] = fmaxf(hn, 0.f); hidF[dd] = fmaxf(hf, 0.f);
        }
        __syncthreads();
        if (t < 32) {
            float p2 = b_ev1[t], q2 = 0.f;
            for (int c = 0; c < 64; ++c) { p2 += tP[c]*W_ev1[c*32+t]; q2 += tQ[c]*W_ev1[c*32+t]; }
            ws[OFF_P2 + i*32+t] = p2;
            ws[OFF_Q2 + i*32+t] = q2;
        }
        if (t == 96) {
            float num = b_ft2[0], den = b_ft2[0];
            for (int c = 0; c < 32; ++c) { num += hidN[c]*W_ft2[c]; den += hidF[c]*W_ft2[c]; }
            float dv = (den == 0.f) ? EPSV : den;
            ws[OFF_NV + i] = num / dv;
        }
    }
    // grid-stride zero-fill of the pred_edge region (NN*64 floats)
    const float4 z4 = make_float4(0.f, 0.f, 0.f, 0.f);
    float4* dst = (float4*)(out + (size_t)NV_N * 64);
    size_t nq = (size_t)NN * 16;  // NN*64/4
    for (size_t q = (size_t)b*256 + t; q < nq; q += (size_t)gridDim.x * 256)
        dst[q] = z4;
}

// K2: A row + degree + count + indicator + active pred_edge rows.
// grid 400 (row i), block 256.
__global__ __launch_bounds__(256) void k2_row(
    const float* __restrict__ NEE,
    const float* __restrict__ W_ev2, const float* __restrict__ b_ev2,
    const float* __restrict__ W_e2e, const float* __restrict__ b_e2e,
    float* __restrict__ ws, float* __restrict__ out)
{
    __shared__ float p2s[32], wev2[32], red[256];
    __shared__ int rcnt[256];
    __shared__ unsigned char flag[NV_N];
    __shared__ int act[NV_N];
    __shared__ int s_cnt;
    int i = blockIdx.x, t = threadIdx.x;
    if (t < 32) { p2s[t] = ws[OFF_P2 + i*32+t]; wev2[t] = W_ev2[t]; }
    __syncthreads();
    float b2 = b_ev2[0];
    float s = 0.f; int cc = 0;
    for (int j = t; j < NV_N; j += 256) {
        float v = b2;
        #pragma unroll
        for (int c = 0; c < 32; ++c) {
            float h = p2s[c] + ws[OFF_Q2 + j*32+c];
            v += fmaxf(h, 0.f) * wev2[c];
        }
        float a = fmaxf(v, 0.f);
        ws[OFF_A + i*NV_N + j] = a;
        bool f = (a >= 1.0f);
        flag[j] = f ? 1 : 0;
        out[IND_BASE + (size_t)i*NV_N + j] = f ? 1.f : 0.f;
        s += a; cc += f ? 1 : 0;
    }
    red[t] = s; rcnt[t] = cc;
    __syncthreads();
    for (int st = 128; st > 0; st >>= 1) {
        if (t < st) { red[t] += red[t+st]; rcnt[t] += rcnt[t+st]; }
        __syncthreads();
    }
    if (t == 0) {
        ws[OFF_DV + i] = rsqrtf(fmaxf(red[0], EPSV));
        ((int*)ws)[OFF_CNT + i] = rcnt[0];
    }
    // wave 0: build this row's ordered active list in smem
    if (t < 64) {
        int base = 0;
        for (int ch = 0; ch < 7; ++ch) {
            int j = ch*64 + t;
            bool f = (j < NV_N) && (flag[j] != 0);
            unsigned long long m = __ballot(f);
            if (f) {
                int pre = __popcll(m & ((1ull << t) - 1ull));
                act[base + pre] = j;
            }
            base += __popcll(m);
        }
        if (t == 0) s_cnt = base;
    }
    __syncthreads();
    // active rows: one wave per active edge (round-robin)
    int cnt = s_cnt, lane = t & 63, w = t >> 6;
    for (int k = w; k < cnt; k += 4) {
        int j = act[k];
        int e = i*NV_N + j;
        float emb = NEE[(size_t)(NV_N + e)*64 + lane];
        float v = b_e2e[lane] + ws[OFF_R + i*64 + lane] + ws[OFF_S + j*64 + lane];
        #pragma unroll
        for (int c = 0; c < 64; ++c) v += __shfl(emb, c) * W_e2e[c*64 + lane];
        out[(size_t)(NV_N + e)*64 + lane] = v;
    }
}

// K3: alpha chain + global compaction + wv (gamma-weighted emb) per active edge.
// grid 400 (node/row i), block 256.
__global__ __launch_bounds__(256) void k3_alpha_compact(
    const float* __restrict__ NEE,
    const float* __restrict__ W3,
    const float* __restrict__ W_alpha, const float* __restrict__ b_alpha,
    const float* __restrict__ W_gamma, const float* __restrict__ b_gamma,
    float* __restrict__ ws, int cap)
{
    __shared__ float part[4][64];
    __shared__ int red[256];
    __shared__ int s_off;
    int i = blockIdx.x, t = threadIdx.x, lane = t & 63, w = t >> 6;
    // offset = sum of counts[r] for r < i
    int os = 0;
    for (int r = t; r < i; r += 256) os += ((const int*)ws)[OFF_CNT + r];
    red[t] = os; __syncthreads();
    for (int st = 128; st > 0; st >>= 1) { if (t < st) red[t] += red[t+st]; __syncthreads(); }
    if (t == 0) s_off = red[0];
    // alpha partials: wave w covers j in [w*100, w*100+100)
    float acc = 0.f;
    for (int j = w*100; j < w*100 + 100; ++j) {
        float coef = ws[OFF_A + i*NV_N + j] * ws[OFF_DV + j];
        acc += coef * NEE[j*64 + lane];
    }
    part[w][lane] = acc;
    __syncthreads();   // also makes s_off visible
    if (w == 0) {
        float nm = (part[0][lane] + part[1][lane] + part[2][lane] + part[3][lane]) * ws[OFF_DV + i];
        float mc = 0.f;
        #pragma unroll
        for (int c = 0; c < 64; ++c) mc += __shfl(nm, c) * W3[c*64 + lane];
        float ar = b_alpha[lane];
        #pragma unroll
        for (int c = 0; c < 64; ++c) ar += __shfl(mc, c) * W_alpha[c*64 + lane];
        ws[OFF_AR + i*64 + lane] = ar;
        float mx = fabsf(ar);
        #pragma unroll
        for (int off = 32; off > 0; off >>= 1) mx = fmaxf(mx, __shfl_xor(mx, off));
        if (lane == 0) atomicMax((unsigned*)(ws + OFF_GMAX), __float_as_uint(mx));
    } else if (w == 1) {
        // ordered compaction of this row into the global list
        int base = 0;
        for (int ch = 0; ch < 7; ++ch) {
            int j = ch*64 + lane;
            float a = (j < NV_N) ? ws[OFF_A + i*NV_N + j] : 0.f;
            bool f = (a >= 1.0f);
            unsigned long long m = __ballot(f);
            if (f) {
                int pre = __popcll(m & ((1ull << lane) - 1ull));
                int slot = s_off + base + pre;
                if (slot < cap) ((int*)ws)[OFF_LIST + slot] = i*NV_N + j;
            }
            base += __popcll(m);
        }
    }
    __syncthreads();
    // wv for this row's actives: wave w takes k = w, w+4, ...
    int cnt = ((const int*)ws)[OFF_CNT + i];
    for (int k = w; k < cnt; k += 4) {
        int slot = s_off + k;
        if (slot >= cap) break;
        int e = ((const int*)ws)[OFF_LIST + slot];
        float emb = NEE[(size_t)(NV_N + e)*64 + lane];
        float g = b_gamma[lane];
        #pragma unroll
        for (int c = 0; c < 64; ++c) g += __shfl(emb, c) * W_gamma[c*64 + lane];
        float mx = g;
        #pragma unroll
        for (int off = 32; off > 0; off >>= 1) mx = fmaxf(mx, __shfl_xor(mx, off));
        float p = __expf(g - mx);
        float ssum = p;
        #pragma unroll
        for (int off = 32; off > 0; off >>= 1) ssum += __shfl_xor(ssum, off);
        ws[OFF_WV + (size_t)slot*64 + lane] = (p / ssum) * emb;
    }
}

// K4: gather-GEMM over compact list (LDS-staged, parallel gathers) + final node out.
// grid 400, block 256.
#define LCHUNK 8192
__global__ __launch_bounds__(256) void k4_final(
    const float* __restrict__ A_ne,
    const float* __restrict__ ws, int cap,
    float* __restrict__ out)
{
    __shared__ float av[LCHUNK];
    __shared__ float part[4][64];
    __shared__ int red[256];
    int i = blockIdx.x, t = threadIdx.x, lane = t & 63, w = t >> 6;
    int os = 0;
    for (int r = t; r < NV_N; r += 256) os += ((const int*)ws)[OFF_CNT + r];
    red[t] = os; __syncthreads();
    for (int st = 128; st > 0; st >>= 1) { if (t < st) red[t] += red[t+st]; __syncthreads(); }
    int nnz = red[0]; if (nnz > cap) nnz = cap;
    const float* Arow = A_ne + (size_t)i * NN;
    float acc = 0.f;
    for (int base = 0; base < nnz; base += LCHUNK) {
        int m = nnz - base; if (m > LCHUNK) m = LCHUNK;
        __syncthreads();  // protect av reuse across chunks
        // parallel gather: each thread loads its own A_ne values (64 addrs/instr)
        for (int l = t; l < m; l += 256) {
            int e = ((const int*)ws)[OFF_LIST + base + l];
            av[l] = Arow[e];
        }
        __syncthreads();
        // accumulate: av broadcast from LDS, wv coalesced from L2
        for (int l = w; l < m; l += 4)
            acc = fmaf(av[l], ws[OFF_WV + (size_t)(base + l)*64 + lane], acc);
    }
    part[w][lane] = acc;
    __syncthreads();
    if (w == 0) {
        float aggr = part[0][lane] + part[1][lane] + part[2][lane] + part[3][lane];
        float amax = fmaxf(__uint_as_float(((const unsigned*)(ws + OFF_GMAX))[0]), EPSV);
        float v = (ws[OFF_AR + i*64 + lane] / amax) * ws[OFF_NV + i] * ws[OFF_V4 + i*64 + lane];
        out[i*64 + lane] = v + aggr;
    }
}

extern "C" void kernel_launch(void* const* d_in, const int* in_sizes, int n_in,
                              void* d_out, int out_size, void* d_ws, size_t ws_size,
                              hipStream_t stream) {
    const float* NEE     = (const float*)d_in[1];
    const float* NFN     = (const float*)d_in[2];
    const float* A_ne    = (const float*)d_in[3];
    const float* W_alpha = (const float*)d_in[5];
    const float* b_alpha = (const float*)d_in[6];
    const float* W_gamma = (const float*)d_in[7];
    const float* b_gamma = (const float*)d_in[8];
    const float* W_n2e   = (const float*)d_in[9];
    const float* b_n2e   = (const float*)d_in[10];
    const float* W_ev1   = (const float*)d_in[11];
    const float* b_ev1   = (const float*)d_in[12];
    const float* W_ev2   = (const float*)d_in[13];
    const float* b_ev2   = (const float*)d_in[14];
    const float* W_ft1   = (const float*)d_in[15];
    const float* b_ft1   = (const float*)d_in[16];
    const float* W_ft2   = (const float*)d_in[17];
    const float* b_ft2   = (const float*)d_in[18];
    const float* W3      = (const float*)d_in[19];
    const float* W4      = (const float*)d_in[20];
    const float* W_e2e   = (const float*)d_in[21];
    const float* b_e2e   = (const float*)d_in[22];
    const float* W_n2e2  = (const float*)d_in[23];
    const float* b_n2e2  = (const float*)d_in[24];
    float* out = (float*)d_out;
    float* ws  = (float*)d_ws;

    long long cap_ll = ((long long)(ws_size / 4) - OFF_WV) / 64;
    int cap = (cap_ll > NN) ? NN : (cap_ll < 0 ? 0 : (int)cap_ll);

    hipLaunchKernelGGL(k0_fill_pre, dim3(2048), dim3(256), 0, stream,
        NEE, NFN, W_n2e, b_n2e, W_n2e2, b_n2e2, W_ev1, b_ev1, W4,
        W_ft1, b_ft1, W_ft2, b_ft2, ws, out);
    hipLaunchKernelGGL(k2_row, dim3(NV_N), dim3(256), 0, stream,
        NEE, W_ev2, b_ev2, W_e2e, b_e2e, ws, out);
    hipLaunchKernelGGL(k3_alpha_compact, dim3(NV_N), dim3(256), 0, stream,
        NEE, W3, W_alpha, b_alpha, W_gamma, b_gamma, ws, cap);
    hipLaunchKernelGGL(k4_final, dim3(NV_N), dim3(256), 0, stream,
        A_ne, ws, cap, out);
}